// Round 1
// baseline (622.841 us; speedup 1.0000x reference)
//
#include <hip/hip_runtime.h>

// Problem constants (from reference): 64 agents, 524288-wide features.
#define NA 64
#define FD 524288

// One thread per feature column d:
//   preload h[:,d], c[:,d] into 128 VGPRs (coalesced dword streams),
//   then for each row i: acc = dot(H[i,:], hv) + dot(C[i,:], cv); tanh; store twice.
// H/C accesses are wave-uniform -> scalar loads (s_load_dwordx8/16), contiguous rows.
__global__ __launch_bounds__(256) void linlayer_kernel(
    const float* __restrict__ h, const float* __restrict__ c,
    const float* __restrict__ Hm, const float* __restrict__ Cm,
    float* __restrict__ out)
{
    const int d = blockIdx.x * blockDim.x + threadIdx.x;

    const float* hp = h + d;
    const float* cp = c + d;

    float hv[NA], cv[NA];
#pragma unroll
    for (int j = 0; j < NA; ++j) {
        hv[j] = hp[(size_t)j * FD];
        cv[j] = cp[(size_t)j * FD];
    }

    float* op0 = out + d;                        // hidden
    float* op1 = out + (size_t)NA * FD + d;      // comm (identical values)

#pragma unroll 1
    for (int i = 0; i < NA; ++i) {
        const float* __restrict__ Hr = Hm + i * NA;  // uniform -> s_load
        const float* __restrict__ Cr = Cm + i * NA;

        // 4 partial accumulators to break the FMA dependence chain.
        float a0 = 0.f, a1 = 0.f, a2 = 0.f, a3 = 0.f;
#pragma unroll
        for (int j = 0; j < NA; j += 2) {
            a0 = fmaf(Hr[j],     hv[j],     a0);
            a1 = fmaf(Cr[j],     cv[j],     a1);
            a2 = fmaf(Hr[j + 1], hv[j + 1], a2);
            a3 = fmaf(Cr[j + 1], cv[j + 1], a3);
        }
        const float acc = (a0 + a1) + (a2 + a3);

        // tanh(x) = 1 - 2/(exp(2x)+1); saturates cleanly (no NaN) for |x| large.
        const float e = __expf(2.0f * acc);
        const float t = 1.0f - 2.0f / (e + 1.0f);

        op0[(size_t)i * FD] = t;
        op1[(size_t)i * FD] = t;
    }
}

extern "C" void kernel_launch(void* const* d_in, const int* in_sizes, int n_in,
                              void* d_out, int out_size, void* d_ws, size_t ws_size,
                              hipStream_t stream) {
    const float* h  = (const float*)d_in[0];
    const float* c  = (const float*)d_in[1];
    const float* Hm = (const float*)d_in[2];
    const float* Cm = (const float*)d_in[3];
    float* out = (float*)d_out;

    dim3 block(256);
    dim3 grid(FD / 256);  // 2048 blocks, one thread per feature column
    hipLaunchKernelGGL(linlayer_kernel, grid, block, 0, stream,
                       h, c, Hm, Cm, out);
}

// Round 2
// 521.114 us; speedup vs baseline: 1.1952x; 1.1952x over previous
//
#include <hip/hip_runtime.h>

// 64 agents, 524288-wide features.
#define NA 64
#define FD 524288

// Accumulator-form: one thread handles TWO feature columns (float2).
// Stream over j (the contraction dim): load h[j][d], c[j][d] ONCE, update all
// 64 row-accumulators with wave-uniform H[i][j], C[i][j] (scalar K$ loads).
// acc[64] (float2) = 128 VGPRs live across the j-loop; every loop touching
// acc[] is fully unrolled so indexing stays static (dynamic index => scratch).
__global__ __launch_bounds__(256) void linlayer_kernel(
    const float* __restrict__ h, const float* __restrict__ c,
    const float* __restrict__ Hm, const float* __restrict__ Cm,
    float* __restrict__ out)
{
    const int d2 = blockIdx.x * blockDim.x + threadIdx.x;  // float2 column idx

    const float2* __restrict__ h2 = (const float2*)h;
    const float2* __restrict__ c2 = (const float2*)c;

    float2 acc[NA];
#pragma unroll
    for (int i = 0; i < NA; ++i) { acc[i].x = 0.f; acc[i].y = 0.f; }

#pragma unroll 1
    for (int j = 0; j < NA; ++j) {
        const float2 hv = h2[(size_t)j * (FD / 2) + d2];
        const float2 cv = c2[(size_t)j * (FD / 2) + d2];
#pragma unroll
        for (int i = 0; i < NA; ++i) {
            const float Hij = Hm[i * NA + j];  // wave-uniform -> s_load (K$)
            const float Cij = Cm[i * NA + j];
            acc[i].x = fmaf(Hij, hv.x, fmaf(Cij, cv.x, acc[i].x));
            acc[i].y = fmaf(Hij, hv.y, fmaf(Cij, cv.y, acc[i].y));
        }
    }

    float2* __restrict__ o0 = (float2*)out + d2;                       // hidden
    float2* __restrict__ o1 = (float2*)out + (size_t)NA * (FD / 2) + d2;  // comm

#pragma unroll
    for (int i = 0; i < NA; ++i) {
        // tanh(x) = 1 - 2/(exp(2x)+1); saturates cleanly, no NaN.
        float2 t;
        {
            const float e = __expf(2.0f * acc[i].x);
            t.x = 1.0f - 2.0f / (e + 1.0f);
        }
        {
            const float e = __expf(2.0f * acc[i].y);
            t.y = 1.0f - 2.0f / (e + 1.0f);
        }
        o0[(size_t)i * (FD / 2)] = t;
        o1[(size_t)i * (FD / 2)] = t;
    }
}

extern "C" void kernel_launch(void* const* d_in, const int* in_sizes, int n_in,
                              void* d_out, int out_size, void* d_ws, size_t ws_size,
                              hipStream_t stream) {
    const float* h  = (const float*)d_in[0];
    const float* c  = (const float*)d_in[1];
    const float* Hm = (const float*)d_in[2];
    const float* Cm = (const float*)d_in[3];
    float* out = (float*)d_out;

    dim3 block(256);
    dim3 grid((FD / 2) / 256);  // 1024 blocks; one float2 column per thread
    hipLaunchKernelGGL(linlayer_kernel, grid, block, 0, stream,
                       h, c, Hm, Cm, out);
}

// Round 3
// 520.953 us; speedup vs baseline: 1.1956x; 1.0003x over previous
//
#include <hip/hip_runtime.h>

// 64 agents, 524288-wide features.
#define NA 64
#define FD 524288
#define FD2 (FD / 2)  // 262144 float2 columns

// Accumulator-form, spill-free: __launch_bounds__(256, 1) lifts the VGPR cap
// so acc[64] (float2, 128 VGPRs) stays in registers (~160 VGPR -> 3 waves/SIMD).
// Each thread handles 2 float2 columns; grid = 512 blocks = 2 blocks/CU, all
// co-resident (no tail). Next-j h/c loads are prefetched during the FMA body.
// H/C reads are wave-uniform -> scalar K$ loads, dual-issue with VALU.
__global__ __launch_bounds__(256, 1) void linlayer_kernel(
    const float* __restrict__ h, const float* __restrict__ c,
    const float* __restrict__ Hm, const float* __restrict__ Cm,
    float* __restrict__ out)
{
    const int tid = blockIdx.x * blockDim.x + threadIdx.x;  // 0..131071

    const float2* __restrict__ h2 = (const float2*)h;
    const float2* __restrict__ c2 = (const float2*)c;
    float2* __restrict__ o2 = (float2*)out;

#pragma unroll 1
    for (int col = 0; col < 2; ++col) {
        const int d2 = tid + col * (FD2 / 2);  // both halves stay coalesced

        float2 acc[NA];
#pragma unroll
        for (int i = 0; i < NA; ++i) { acc[i].x = 0.f; acc[i].y = 0.f; }

        // software pipeline: hv/cv hold iteration j, hn/cn prefetch j+1
        float2 hv = h2[d2];
        float2 cv = c2[d2];

#pragma unroll 1
        for (int j = 0; j < NA; ++j) {
            const int jn = (j + 1) & (NA - 1);  // clamped wrap: avoids a branch
            const float2 hn = h2[(size_t)jn * FD2 + d2];
            const float2 cn = c2[(size_t)jn * FD2 + d2];
#pragma unroll
            for (int i = 0; i < NA; ++i) {
                const float Hij = Hm[i * NA + j];  // wave-uniform -> s_load
                const float Cij = Cm[i * NA + j];
                acc[i].x = fmaf(Hij, hv.x, fmaf(Cij, cv.x, acc[i].x));
                acc[i].y = fmaf(Hij, hv.y, fmaf(Cij, cv.y, acc[i].y));
            }
            hv = hn; cv = cn;
        }

#pragma unroll
        for (int i = 0; i < NA; ++i) {
            // tanh(x) = 1 - 2/(exp(2x)+1); saturates cleanly, no NaN.
            float2 t;
            {
                const float e = __expf(2.0f * acc[i].x);
                t.x = 1.0f - 2.0f / (e + 1.0f);
            }
            {
                const float e = __expf(2.0f * acc[i].y);
                t.y = 1.0f - 2.0f / (e + 1.0f);
            }
            o2[(size_t)i * FD2 + d2] = t;              // hidden
            o2[(size_t)(NA + i) * FD2 + d2] = t;       // comm (same values)
        }
    }
}

extern "C" void kernel_launch(void* const* d_in, const int* in_sizes, int n_in,
                              void* d_out, int out_size, void* d_ws, size_t ws_size,
                              hipStream_t stream) {
    const float* h  = (const float*)d_in[0];
    const float* c  = (const float*)d_in[1];
    const float* Hm = (const float*)d_in[2];
    const float* Cm = (const float*)d_in[3];
    float* out = (float*)d_out;

    dim3 block(256);
    dim3 grid((FD2 / 2) / 256);  // 512 blocks; 2 float2 columns per thread
    hipLaunchKernelGGL(linlayer_kernel, grid, block, 0, stream,
                       h, c, Hm, Cm, out);
}